// Round 4
// baseline (5536.397 us; speedup 1.0000x reference)
//
#include <hip/hip_runtime.h>
#include <math.h>

#define T_ 32
#define B_ 16
#define V_ 30000
#define V4 7500
#define D_ 300
#define DQKV_ 150
#define K_ 10
#define G_ 32
#define N_ 320      // K*G
#define S_ 25000
#define S4 6250
#define NT 1024
#define NWAVES 16

__device__ __forceinline__ bool better(float av, int ai, float bv, int bi) {
    // ranks (av,ai) strictly before (bv,bi): higher value, ties -> lower index
    return (av > bv) || (av == bv && ai < bi);
}

__global__ __launch_bounds__(NT, 8) void selfatt_fused(
    const float* __restrict__ pred,   // [T*B, V]
    const float* __restrict__ lc,     // [T*B, D]
    const float* __restrict__ SC,     // [S, D]
    const float* __restrict__ Wq,     // [D, DQKV]
    const float* __restrict__ Wk,     // [D, DQKV]
    const int*   __restrict__ nbt,    // [V, G] int32
    float* __restrict__ out)          // [T*B, S]
{
    const int row  = blockIdx.x;
    const int tid  = threadIdx.x;
    const int lane = tid & 63;
    const int wave = tid >> 6;

    __shared__ float wcv[NWAVES * K_];
    __shared__ int   wci[NWAVES * K_];
    __shared__ int   topg[K_];
    __shared__ float lcs[D_];
    __shared__ float qs[DQKV_];
    __shared__ __align__(16) float qks[D_];
    __shared__ int   nidx[N_];
    __shared__ float lg[N_];
    __shared__ int   kills[N_];
    __shared__ float redA[NWAVES], redB[NWAVES];

    float* outrow = out + (size_t)row * S_;
    const float FILL = -18.420680743952367f;   // log(1e-8)

    // ---- P0: fill output row (stores drain at first barrier; overlaps scan) ----
    {
        float4 f4 = make_float4(FILL, FILL, FILL, FILL);
        float4* o4 = (float4*)outrow;
        #pragma unroll
        for (int k = 0; k < 7; ++k) {
            int i = tid + k * NT;
            if (i < S4) o4[i] = f4;
        }
    }

    // ---- P1: per-thread top-10 over ~30 logits, staged 4 float4 at a time ----
    float tv[K_]; int ti[K_];
    #pragma unroll
    for (int s = 0; s < K_; ++s) { tv[s] = -INFINITY; ti[s] = 0x7fffffff; }
    {
        const float4* p4 = (const float4*)(pred + (size_t)row * V_);
        const float4 NEG = make_float4(-INFINITY, -INFINITY, -INFINITY, -INFINITY);
        for (int kb = 0; kb < 2; ++kb) {
            float4 a[4]; int ib[4];
            #pragma unroll
            for (int u = 0; u < 4; ++u) {
                int i = tid + (kb * 4 + u) * NT;
                a[u]  = (i < V4) ? p4[i] : NEG;
                ib[u] = (i < V4) ? i * 4 : 0x7ffffffc;   // +c stays <= INT_MAX
            }
            #pragma unroll
            for (int u = 0; u < 4; ++u) {
                float vals[4] = {a[u].x, a[u].y, a[u].z, a[u].w};
                #pragma unroll
                for (int c = 0; c < 4; ++c) {
                    float val = vals[c];
                    int   idx = ib[u] + c;
                    if (better(val, idx, tv[K_-1], ti[K_-1])) {
                        tv[K_-1] = val; ti[K_-1] = idx;
                        #pragma unroll
                        for (int s = K_-1; s > 0; --s) {
                            if (better(tv[s], ti[s], tv[s-1], ti[s-1])) {
                                float x = tv[s]; tv[s] = tv[s-1]; tv[s-1] = x;
                                int   y = ti[s]; ti[s] = ti[s-1]; ti[s-1] = y;
                            }
                        }
                    }
                }
            }
        }
    }

    // ---- P2: per-wave top-10 via 10 shfl-argmax passes (no barriers) ----
    for (int p = 0; p < K_; ++p) {
        float bv = tv[0]; int bi = ti[0];
        #pragma unroll
        for (int s = 1; s < K_; ++s)
            if (better(tv[s], ti[s], bv, bi)) { bv = tv[s]; bi = ti[s]; }
        #pragma unroll
        for (int off = 32; off; off >>= 1) {
            float ov = __shfl_xor(bv, off, 64);
            int   oi = __shfl_xor(bi, off, 64);
            if (better(ov, oi, bv, bi)) { bv = ov; bi = oi; }
        }
        if (lane == 0) { wcv[wave * K_ + p] = bv; wci[wave * K_ + p] = bi; }
        #pragma unroll
        for (int s = 0; s < K_; ++s)
            if (ti[s] == bi) tv[s] = -INFINITY;
    }
    __syncthreads();                                   // BAR1

    // ---- P3: wave 0 merges 160 candidates -> global top-10 (no barriers) ----
    if (wave == 0) {
        float c0v = wcv[lane],      c1v = wcv[64 + lane];
        int   c0i = wci[lane],      c1i = wci[64 + lane];
        float c2v = (lane < 32) ? wcv[128 + lane] : -INFINITY;
        int   c2i = (lane < 32) ? wci[128 + lane] : 0x7fffffff;
        for (int p = 0; p < K_; ++p) {
            float bv = c0v; int bi = c0i;
            if (better(c1v, c1i, bv, bi)) { bv = c1v; bi = c1i; }
            if (better(c2v, c2i, bv, bi)) { bv = c2v; bi = c2i; }
            #pragma unroll
            for (int off = 32; off; off >>= 1) {
                float ov = __shfl_xor(bv, off, 64);
                int   oi = __shfl_xor(bi, off, 64);
                if (better(ov, oi, bv, bi)) { bv = ov; bi = oi; }
            }
            if (lane == 0) topg[p] = bi;
            if (c0i == bi) c0v = -INFINITY;
            if (c1i == bi) c1v = -INFINITY;
            if (c2i == bi) c2v = -INFINITY;
        }
    }
    __syncthreads();                                   // BAR2

    // ---- P4: neighbours / kill-flag zero / location-context, disjoint threads ----
    if (tid < N_) {
        int g = topg[tid >> 5];
        nidx[tid] = nbt[g * G_ + (tid & 31)];
    } else if (tid < 2 * N_) {
        kills[tid - N_] = 0;
    } else if (tid >= 640 && tid < 640 + D_) {
        lcs[tid - 640] = lc[(size_t)row * D_ + (tid - 640)];
    }
    __syncthreads();                                   // BAR3

    // ---- P5: q = lcs @ Wq (600 threads, 4-way dots) ∥ dup-scan (424 threads) ----
    if (tid < 600) {
        int j = tid >> 2, h = tid & 3;
        int d0 = h * 75;
        const float* wp = Wq + (size_t)d0 * DQKV_ + j;
        float acc = 0.f;
        #pragma unroll 5
        for (int dd = 0; dd < 75; ++dd) acc += lcs[d0 + dd] * wp[(size_t)dd * DQKV_];
        acc += __shfl_xor(acc, 1, 64);
        acc += __shfl_xor(acc, 2, 64);
        if (h == 0) qs[j] = acc;
    } else {
        // last-write-wins duplicate detection: 1280 chunk-scans of width 80
        int t0 = tid - 600;                 // 0..423
        for (int s = t0; s < 4 * N_; s += 424) {
            int n = s >> 2, c = s & 3;
            int sidx = nidx[n];
            int clo = c * 80;
            int lo = (n + 1 > clo) ? n + 1 : clo;
            int hi = clo + 80;
            bool mt = false;
            #pragma unroll 4
            for (int n2 = lo; n2 < hi; ++n2) mt |= (nidx[n2] == sidx);
            if (mt) kills[n] = 1;           // n is not the last occurrence
        }
    }
    __syncthreads();                                   // BAR4

    // ---- P6: qk[d] = Wk[d,:].q (600 threads, 2-way dots) ----
    if (tid < 600) {
        int d = tid >> 1, h = tid & 1;
        int j0 = h * 75;
        const float* wrow = Wk + (size_t)d * DQKV_ + j0;
        float acc = 0.f;
        #pragma unroll 5
        for (int jj = 0; jj < 75; ++jj) acc += wrow[jj] * qs[j0 + jj];
        acc += __shfl_xor(acc, 1, 64);
        if (h == 0) qks[d] = acc;
    }
    __syncthreads();                                   // BAR5

    // ---- P7: logits[n] = (qk . SC[nidx[n]])/sqrt(150), 8 lanes per dot ----
    const float ISC = 0.08164965809277260327f;   // 1/sqrt(150)
    const float4* q4 = (const float4*)qks;
    for (int s = tid; s < 8 * N_; s += NT) {     // 2560 lane-slots
        int n = s >> 3, h = s & 7;
        const float4* sc4 = (const float4*)(SC + (size_t)nidx[n] * D_);
        int c0 = h * 9;
        float acc = 0.f;
        #pragma unroll 3
        for (int cc = 0; cc < 9; ++cc) {
            float4 a = sc4[c0 + cc];
            float4 b = q4[c0 + cc];
            acc += a.x * b.x + a.y * b.y + a.z * b.z + a.w * b.w;
        }
        if (h < 3) {                              // chunks 72..74
            float4 a = sc4[72 + h];
            float4 b = q4[72 + h];
            acc += a.x * b.x + a.y * b.y + a.z * b.z + a.w * b.w;
        }
        acc += __shfl_xor(acc, 1, 64);
        acc += __shfl_xor(acc, 2, 64);
        acc += __shfl_xor(acc, 4, 64);
        if (h == 0) lg[n] = acc * ISC;
    }
    __syncthreads();                                   // BAR6

    // ---- P8: softmax stats (two cross-wave reductions) ----
    float v = (tid < N_) ? lg[tid] : -INFINITY;
    float m = v;
    #pragma unroll
    for (int off = 32; off; off >>= 1) m = fmaxf(m, __shfl_xor(m, off, 64));
    if (lane == 0) redA[wave] = m;
    __syncthreads();                                   // BAR7
    m = redA[0];
    #pragma unroll
    for (int w = 1; w < NWAVES; ++w) m = fmaxf(m, redA[w]);

    float e = (tid < N_) ? expf(v - m) : 0.f;
    float ss = e;
    #pragma unroll
    for (int off = 32; off; off >>= 1) ss += __shfl_xor(ss, off, 64);
    if (lane == 0) redB[wave] = ss;
    __syncthreads();                                   // BAR8
    float tot = redB[0];
    #pragma unroll
    for (int w = 1; w < NWAVES; ++w) tot += redB[w];
    float lsum = logf(tot);

    // ---- P9: scatter log-probs (fill stores drained at BAR1..BAR8) ----
    if (tid < N_ && !kills[tid]) outrow[nidx[tid]] = (v - m) - lsum;
}

extern "C" void kernel_launch(void* const* d_in, const int* in_sizes, int n_in,
                              void* d_out, int out_size, void* d_ws, size_t ws_size,
                              hipStream_t stream) {
    const float* pred = (const float*)d_in[0];
    const float* lc   = (const float*)d_in[1];
    const float* SC   = (const float*)d_in[2];
    const float* Wq   = (const float*)d_in[3];
    const float* Wk   = (const float*)d_in[4];
    const int*   nbt  = (const int*)d_in[5];
    float* out = (float*)d_out;

    selfatt_fused<<<dim3(T_ * B_), dim3(NT), 0, stream>>>(
        pred, lc, SC, Wq, Wk, nbt, out);
}

// Round 5
// 206.905 us; speedup vs baseline: 26.7581x; 26.7581x over previous
//
#include <hip/hip_runtime.h>
#include <math.h>

#define T_ 32
#define B_ 16
#define V_ 30000
#define V4 7500
#define D_ 300
#define DQKV_ 150
#define K_ 10
#define G_ 32
#define N_ 320      // K*G
#define S_ 25000
#define S4 6250
#define NT 1024
#define NWAVES 16

__device__ __forceinline__ bool better(float av, int ai, float bv, int bi) {
    // ranks (av,ai) strictly before (bv,bi): higher value, ties -> lower index
    return (av > bv) || (av == bv && ai < bi);
}

// NOTE: 2nd launch-bounds arg = min waves per EU. 8 forced VGPR<=32 -> mass
// scratch spill (22 GB writes/dispatch, R3). 4 -> VGPR cap 128, no spill.
__global__ __launch_bounds__(NT, 4) void selfatt_fused(
    const float* __restrict__ pred,   // [T*B, V]
    const float* __restrict__ lc,     // [T*B, D]
    const float* __restrict__ SC,     // [S, D]
    const float* __restrict__ Wq,     // [D, DQKV]
    const float* __restrict__ Wk,     // [D, DQKV]
    const int*   __restrict__ nbt,    // [V, G] int32
    float* __restrict__ out)          // [T*B, S]
{
    const int row  = blockIdx.x;
    const int tid  = threadIdx.x;
    const int lane = tid & 63;
    const int wave = tid >> 6;

    __shared__ float wcv[NWAVES * K_];
    __shared__ int   wci[NWAVES * K_];
    __shared__ int   topg[K_];
    __shared__ float lcs[D_];
    __shared__ float qs[DQKV_];
    __shared__ __align__(16) float qks[D_];
    __shared__ int   nidx[N_];
    __shared__ float lg[N_];
    __shared__ int   kills[N_];
    __shared__ float redA[NWAVES], redB[NWAVES];

    float* outrow = out + (size_t)row * S_;
    const float FILL = -18.420680743952367f;   // log(1e-8)

    // ---- P0: fill output row (stores drain by first barrier; overlaps scan) ----
    {
        float4 f4 = make_float4(FILL, FILL, FILL, FILL);
        float4* o4 = (float4*)outrow;
        #pragma unroll
        for (int k = 0; k < 7; ++k) {
            int i = tid + k * NT;
            if (i < S4) o4[i] = f4;
        }
    }

    // ---- P1: per-thread top-10 over ~30 logits, staged 2 float4 at a time ----
    float tv[K_]; int ti[K_];
    #pragma unroll
    for (int s = 0; s < K_; ++s) { tv[s] = -INFINITY; ti[s] = 0x7fffffff; }
    {
        const float4* p4 = (const float4*)(pred + (size_t)row * V_);
        const float4 NEG = make_float4(-INFINITY, -INFINITY, -INFINITY, -INFINITY);
        for (int kb = 0; kb < 4; ++kb) {
            float4 a0, a1; int i0, i1;
            {
                int i = tid + (kb * 2 + 0) * NT;
                a0 = (i < V4) ? p4[i] : NEG;
                i0 = (i < V4) ? i * 4 : 0x7ffffffb;
                int j = tid + (kb * 2 + 1) * NT;
                a1 = (j < V4) ? p4[j] : NEG;
                i1 = (j < V4) ? j * 4 : 0x7ffffffb;
            }
            float4 vv[2] = {a0, a1};
            int    ib[2] = {i0, i1};
            #pragma unroll
            for (int u = 0; u < 2; ++u) {
                float vals[4] = {vv[u].x, vv[u].y, vv[u].z, vv[u].w};
                #pragma unroll
                for (int c = 0; c < 4; ++c) {
                    float val = vals[c];
                    int   idx = ib[u] + c;
                    if (better(val, idx, tv[K_-1], ti[K_-1])) {
                        tv[K_-1] = val; ti[K_-1] = idx;
                        #pragma unroll
                        for (int s = K_-1; s > 0; --s) {
                            if (better(tv[s], ti[s], tv[s-1], ti[s-1])) {
                                float x = tv[s]; tv[s] = tv[s-1]; tv[s-1] = x;
                                int   y = ti[s]; ti[s] = ti[s-1]; ti[s-1] = y;
                            }
                        }
                    }
                }
            }
        }
    }

    // ---- P2: per-wave top-10 via 10 shfl-argmax passes (no barriers) ----
    for (int p = 0; p < K_; ++p) {
        float bv = tv[0]; int bi = ti[0];
        #pragma unroll
        for (int s = 1; s < K_; ++s)
            if (better(tv[s], ti[s], bv, bi)) { bv = tv[s]; bi = ti[s]; }
        #pragma unroll
        for (int off = 32; off; off >>= 1) {
            float ov = __shfl_xor(bv, off, 64);
            int   oi = __shfl_xor(bi, off, 64);
            if (better(ov, oi, bv, bi)) { bv = ov; bi = oi; }
        }
        if (lane == 0) { wcv[wave * K_ + p] = bv; wci[wave * K_ + p] = bi; }
        #pragma unroll
        for (int s = 0; s < K_; ++s)
            if (ti[s] == bi) tv[s] = -INFINITY;
    }
    __syncthreads();                                   // BAR1

    // ---- P3: wave 0 merges 160 candidates -> global top-10 (no barriers) ----
    if (wave == 0) {
        float c0v = wcv[lane],      c1v = wcv[64 + lane];
        int   c0i = wci[lane],      c1i = wci[64 + lane];
        float c2v = (lane < 32) ? wcv[128 + lane] : -INFINITY;
        int   c2i = (lane < 32) ? wci[128 + lane] : 0x7fffffff;
        for (int p = 0; p < K_; ++p) {
            float bv = c0v; int bi = c0i;
            if (better(c1v, c1i, bv, bi)) { bv = c1v; bi = c1i; }
            if (better(c2v, c2i, bv, bi)) { bv = c2v; bi = c2i; }
            #pragma unroll
            for (int off = 32; off; off >>= 1) {
                float ov = __shfl_xor(bv, off, 64);
                int   oi = __shfl_xor(bi, off, 64);
                if (better(ov, oi, bv, bi)) { bv = ov; bi = oi; }
            }
            if (lane == 0) topg[p] = bi;
            if (c0i == bi) c0v = -INFINITY;
            if (c1i == bi) c1v = -INFINITY;
            if (c2i == bi) c2v = -INFINITY;
        }
    }
    __syncthreads();                                   // BAR2

    // ---- P4: neighbours / kill-flag zero / location-context, disjoint threads ----
    if (tid < N_) {
        int g = topg[tid >> 5];
        nidx[tid] = nbt[g * G_ + (tid & 31)];
    } else if (tid < 2 * N_) {
        kills[tid - N_] = 0;
    } else if (tid >= 640 && tid < 640 + D_) {
        lcs[tid - 640] = lc[(size_t)row * D_ + (tid - 640)];
    }
    __syncthreads();                                   // BAR3

    // ---- P5: q = lcs @ Wq (600 threads, 4-way dots) ∥ dup-scan (424 threads) ----
    if (tid < 600) {
        int j = tid >> 2, h = tid & 3;
        int d0 = h * 75;
        const float* wp = Wq + (size_t)d0 * DQKV_ + j;
        float acc = 0.f;
        #pragma unroll 5
        for (int dd = 0; dd < 75; ++dd) acc += lcs[d0 + dd] * wp[(size_t)dd * DQKV_];
        acc += __shfl_xor(acc, 1, 64);
        acc += __shfl_xor(acc, 2, 64);
        if (h == 0) qs[j] = acc;
    } else {
        // last-write-wins duplicate detection: 1280 chunk-scans of width 80
        int t0 = tid - 600;                 // 0..423
        for (int s = t0; s < 4 * N_; s += 424) {
            int n = s >> 2, c = s & 3;
            int sidx = nidx[n];
            int clo = c * 80;
            int lo = (n + 1 > clo) ? n + 1 : clo;
            int hi = clo + 80;
            bool mt = false;
            #pragma unroll 4
            for (int n2 = lo; n2 < hi; ++n2) mt |= (nidx[n2] == sidx);
            if (mt) kills[n] = 1;           // n is not the last occurrence
        }
    }
    __syncthreads();                                   // BAR4

    // ---- P6: qk[d] = Wk[d,:].q (600 threads, 2-way dots) ----
    if (tid < 600) {
        int d = tid >> 1, h = tid & 1;
        int j0 = h * 75;
        const float* wrow = Wk + (size_t)d * DQKV_ + j0;
        float acc = 0.f;
        #pragma unroll 5
        for (int jj = 0; jj < 75; ++jj) acc += wrow[jj] * qs[j0 + jj];
        acc += __shfl_xor(acc, 1, 64);
        if (h == 0) qks[d] = acc;
    }
    __syncthreads();                                   // BAR5

    // ---- P7: logits[n] = (qk . SC[nidx[n]])/sqrt(150), 8 lanes per dot ----
    const float ISC = 0.08164965809277260327f;   // 1/sqrt(150)
    const float4* q4 = (const float4*)qks;
    for (int s = tid; s < 8 * N_; s += NT) {     // 2560 lane-slots
        int n = s >> 3, h = s & 7;
        const float4* sc4 = (const float4*)(SC + (size_t)nidx[n] * D_);
        int c0 = h * 9;
        float acc = 0.f;
        #pragma unroll 3
        for (int cc = 0; cc < 9; ++cc) {
            float4 a = sc4[c0 + cc];
            float4 b = q4[c0 + cc];
            acc += a.x * b.x + a.y * b.y + a.z * b.z + a.w * b.w;
        }
        if (h < 3) {                              // chunks 72..74
            float4 a = sc4[72 + h];
            float4 b = q4[72 + h];
            acc += a.x * b.x + a.y * b.y + a.z * b.z + a.w * b.w;
        }
        acc += __shfl_xor(acc, 1, 64);
        acc += __shfl_xor(acc, 2, 64);
        acc += __shfl_xor(acc, 4, 64);
        if (h == 0) lg[n] = acc * ISC;
    }
    __syncthreads();                                   // BAR6

    // ---- P8: softmax stats (two cross-wave reductions) ----
    float v = (tid < N_) ? lg[tid] : -INFINITY;
    float m = v;
    #pragma unroll
    for (int off = 32; off; off >>= 1) m = fmaxf(m, __shfl_xor(m, off, 64));
    if (lane == 0) redA[wave] = m;
    __syncthreads();                                   // BAR7
    m = redA[0];
    #pragma unroll
    for (int w = 1; w < NWAVES; ++w) m = fmaxf(m, redA[w]);

    float e = (tid < N_) ? expf(v - m) : 0.f;
    float ss = e;
    #pragma unroll
    for (int off = 32; off; off >>= 1) ss += __shfl_xor(ss, off, 64);
    if (lane == 0) redB[wave] = ss;
    __syncthreads();                                   // BAR8
    float tot = redB[0];
    #pragma unroll
    for (int w = 1; w < NWAVES; ++w) tot += redB[w];
    float lsum = logf(tot);

    // ---- P9: scatter log-probs (fill stores drained at BAR1..BAR8) ----
    if (tid < N_ && !kills[tid]) outrow[nidx[tid]] = (v - m) - lsum;
}

extern "C" void kernel_launch(void* const* d_in, const int* in_sizes, int n_in,
                              void* d_out, int out_size, void* d_ws, size_t ws_size,
                              hipStream_t stream) {
    const float* pred = (const float*)d_in[0];
    const float* lc   = (const float*)d_in[1];
    const float* SC   = (const float*)d_in[2];
    const float* Wq   = (const float*)d_in[3];
    const float* Wk   = (const float*)d_in[4];
    const int*   nbt  = (const int*)d_in[5];
    float* out = (float*)d_out;

    selfatt_fused<<<dim3(T_ * B_), dim3(NT), 0, stream>>>(
        pred, lc, SC, Wq, Wk, nbt, out);
}